// Round 14
// baseline (6104.242 us; speedup 1.0000x reference)
//
#include <hip/hip_runtime.h>

// RNNModel: 2-layer LSTM (B=64,T=400,E=H=500) + MLP head (800->100->2).
// Round 14: r11 (best, 5.78ms) + odd-capable weight-LDS swizzle.
//  - r11's w-read quad-pos 2(cg^ks) is even-only -> 8-way bank conflict
//    (odd bank groups idle). New: stored quad q of row r holds logical
//    quad q ^ g(r&3), g(k)=(2k)^k in {0,3,6,5}; read quad-pos 2cg ^ g(ks).
//    Per conflict set the 4 ks-lanes hit 4 distinct quad-positions -> <=4-way.
//    Realized on the gll SOURCE col (dest linear, rule #21); logical cols per
//    lane unchanged -> acc/reduce/partials/gates byte-identical to r11.
//  - everything else r11 verbatim: dispatch-per-step, xe pre-pass
//    (ws-guarded), unified pure-gll staging, wave-local weight rows, depth-1
//    prefetch + counted vmcnt(4), 8col x 8batch tile, DPP ks-reduce,
//    ONE __syncthreads, f64 combine/gates/cell (absmax-0.0 family).

#define NTHR 512
#define Tn 400
#define Hn 500

#define OFF_H1 0            // float [2][500*64] transposed h1
#define OFF_H2 256000       // float [2][500*64] transposed h2
#define OFF_C1 512000       // double [500*64] c1 (index u*64+b)
#define OFF_C2 768000       // double [500*64] c2
#define OFF_D1 1024000      // float [64*800]
#define OFF_D2 1228800      // float [64*100]
#define OFF_XE 1254400      // float [400][500][64] transposed embed gather
#define WS_NEED (1254400ull + 51200000ull)
#define WS_ZERO 1024000     // zero h+c; d1/d2/xe fully overwritten

__device__ __forceinline__ float qreduce(float v) {
    // butterfly over lanes ^1 and ^2 (quad_perm DPP, pure VALU pipe)
    int t = __builtin_amdgcn_update_dpp(0, __float_as_int(v), 0xB1, 0xF, 0xF, true);
    v += __int_as_float(t);
    t = __builtin_amdgcn_update_dpp(0, __float_as_int(v), 0x4E, 0xF, 0xF, true);
    v += __int_as_float(t);
    return v;
}

__device__ __forceinline__ int wrow_map(int r) {
    // padded LDS row -> global weight row (zero-x rows: any valid row)
    int r2 = (r >= 512) ? r - 12 : r;
    if ((r >= 500 && r < 512) || r >= 1012) r2 = 0;
    return r2;
}

// ---------- pre-pass: xe[t][k][b] = embed[X[b][t]][k] ----------
extern "C" __global__ void __launch_bounds__(256)
xprep(const int* __restrict__ X, const float* __restrict__ embed,
      float* __restrict__ xe)
{
    const int t = blockIdx.x;           // 400 blocks
    const int b = threadIdx.x & 63;
    const int kq0 = threadIdx.x >> 6;   // 0..3
    const float* er = embed + (size_t)X[b * Tn + t] * 500;
    float* dst = xe + (size_t)t * 32000;
    for (int kq = kq0; kq < 125; kq += 4) {
        const float4 v = *(const float4*)(er + 4 * kq);
        dst[(4 * kq + 0) * 64 + b] = v.x;
        dst[(4 * kq + 1) * 64 + b] = v.y;
        dst[(4 * kq + 2) * 64 + b] = v.z;
        dst[(4 * kq + 3) * 64 + b] = v.w;
    }
}

extern "C" __global__ void __launch_bounds__(NTHR)
rnn_step(const int* __restrict__ X, const float* __restrict__ embed,
         const float* __restrict__ k1, const float* __restrict__ b1g,
         const float* __restrict__ k2, const float* __restrict__ b2g,
         char* __restrict__ ws, const float* __restrict__ xe, int use_xe,
         int s)
{
    __shared__ float s_x[16384];     // [1024 padded-k][16 b]
    __shared__ float s_w[2][8192];   // dbuf [128 rows][64 cols, row-XOR swz]
    // partials alias s_w[0]: wave w's segment == its own rows 16w..16w+15

    float* h1b = (float*)(ws + OFF_H1);
    float* h2b = (float*)(ws + OFF_H2);

    const int bid = blockIdx.x;
    const int tid = threadIdx.x;
    const int rr_ = bid >> 3;
    const int slice = (bid & 7) * 8 + (rr_ >> 2);  // XCD-grouped duplicates
    const int btile = rr_ & 3;
    const int L = slice >> 5;
    const int ut = slice & 31;          // units ut*16..+15
    const int b0 = btile * 16;

    const bool active = L ? (s >= 1) : (s < Tn);
    if (!active) return;

    const int w = tid >> 6;             // wave
    const int l = tid & 63;
    const int ks = l & 3;               // K sublane
    const int cg = (l >> 2) & 7;        // 8-col group
    const int bg = l >> 5;              // 8-batch half

    const float* Wm = L ? k2 : k1;      // [1000][2000], col = g*500+u
    const float* bv = L ? b2g : b1g;
    double* cb = (double*)(ws + (L ? OFF_C2 : OFF_C1));

    const int cur = s & 1, prv = cur ^ 1;
    const float* h1p = h1b + prv * 32000;
    const float* h2p = h2b + prv * 32000;
    float* houtT = (L ? h2b : h1b) + cur * 32000;
    const int t = L ? (s - 1) : s;
    const float* hlow = h1p;                    // padded rows 0..499
    const float* hhigh = L ? h2p : h1p;         // padded rows 512..1011

    // ---- weight gll source mapping (dest linear; source col permuted) ----
    // stored quad q at row r holds logical quad q ^ g(r&3), g(k)=(2k)^k
    const int wdr = l >> 4;                     // dest row within 4-row inst
    const int wcq = l & 15;
    const int gw = ((wdr << 1) ^ wdr);          // g(wdr) in {0,3,6,5}
    const int c_l = (4 * wcq) ^ (gw << 2);      // logical float col for lane
    const int wcol = (c_l >> 4) * 500 + min(ut * 16 + (c_l & 15), 496);

    // ---- x gll lane consts ----
    const int xr4 = l >> 2;
    const int xj = (l & 3) * 4;

    // ---- w-read offsets: quad-pos = 2cg ^ g(ks) (odd-capable, <=4-way) ----
    const int gks = ((ks << 1) ^ ks);           // g(ks) in {0,3,6,5}
    const int woffA = (((cg << 1) ^ gks) << 2); // float offset of logical 2cg
    const int woffB = woffA ^ 4;                // logical quad 2cg+1

    // =================== x staging (wave-local rows) ===================
    if (use_xe || L == 1) {
        // unified pure-gll path
        const float* srcLow = L ? hlow : (xe + (size_t)t * 32000);
        const float* srcHigh = hhigh;
        #pragma unroll
        for (int c = 0; c < 8; ++c) {
            if (w < 7 || (c != 3 && c != 7)) {
                const int base = 128 * c + 16 * w;
                const float* src = (c < 4)
                    ? (srcLow + (base + xr4) * 64 + b0 + xj)
                    : (srcHigh + (base - 512 + xr4) * 64 + b0 + xj);
                __builtin_amdgcn_global_load_lds(src, &s_x[base * 16], 16, 0, 0);
            }
        }
        if (w == 7) {
            if (l < 16) {
                const int r = 496 + (l >> 2);       // <- srcLow rows 496..499
                const float4 v = *(const float4*)(srcLow + r * 64 + b0 + (l & 3) * 4);
                *(float4*)&s_x[r * 16 + (l & 3) * 4] = v;
                const int r2 = 1008 + (l >> 2);     // <- srcHigh rows 496..499
                const float4 v2 = *(const float4*)(srcHigh + (r2 - 512) * 64 + b0 + (l & 3) * 4);
                *(float4*)&s_x[r2 * 16 + (l & 3) * 4] = v2;
            }
            if (l < 48) {
                const int r = 500 + (l >> 2);
                *(float4*)&s_x[r * 16 + 4 * (l & 3)] = make_float4(0.f, 0.f, 0.f, 0.f);
                const int r2 = 1012 + (l >> 2);
                *(float4*)&s_x[r2 * 16 + 4 * (l & 3)] = make_float4(0.f, 0.f, 0.f, 0.f);
            }
        }
    } else {
        // fallback (ws too small): r8's L0 embed-transpose path, verbatim
        const int eb = l & 15, j = l >> 4;
        const int xid = X[(b0 + eb) * Tn + t];
        const float* er = embed + (size_t)xid * 500;
        #pragma unroll
        for (int c = 0; c < 4; ++c) {
            if (w < 7 || c < 3) {
                const int base = 128 * c + 16 * w;
                const float4 v = *(const float4*)(er + base + 4 * j);
                float* d = &s_x[(base + 4 * j) * 16 + eb];
                d[0] = v.x; d[16] = v.y; d[32] = v.z; d[48] = v.w;
            }
        }
        #pragma unroll
        for (int c = 4; c < 8; ++c) {
            if (!(w == 7 && c == 7)) {
                const int base = 128 * c + 16 * w;
                const float* src = hhigh + (base - 512 + xr4) * 64 + b0 + xj;
                __builtin_amdgcn_global_load_lds(src, &s_x[base * 16], 16, 0, 0);
            }
        }
        if (w == 7) {
            {   // rows 496..499 <- embed cols 496..499
                const int r = 496 + (l >> 4);
                const int b = l & 15;
                const float vv = embed[(size_t)X[(b0 + b) * Tn + t] * 500 + r];
                s_x[r * 16 + b] = vv;
            }
            if (l < 16) {               // rows 1008..1011 <- h1 rows 496..499
                const int r = 1008 + (l >> 2);
                const float4 v = *(const float4*)(hhigh + (r - 512) * 64 + b0 + (l & 3) * 4);
                *(float4*)&s_x[r * 16 + (l & 3) * 4] = v;
            }
            if (l < 48) {               // zero rows 500..511, 1012..1023
                const int r = 500 + (l >> 2);
                *(float4*)&s_x[r * 16 + 4 * (l & 3)] = make_float4(0.f, 0.f, 0.f, 0.f);
                const int r2 = 1012 + (l >> 2);
                *(float4*)&s_x[r2 * 16 + 4 * (l & 3)] = make_float4(0.f, 0.f, 0.f, 0.f);
            }
        }
    }
    // weight chunk 0 (wave-local rows)
    #pragma unroll
    for (int q = 0; q < 4; ++q) {
        const int lr = 16 * w + 4 * q;
        const int gr = wrow_map(lr + wdr);
        __builtin_amdgcn_global_load_lds(Wm + (size_t)gr * 2000 + wcol,
                                         &s_w[0][lr * 64], 16, 0, 0);
    }

    // ================= chunk loop: NO barriers, counted vmcnt ===========
    float4 acc[8][2];
    #pragma unroll
    for (int cc = 0; cc < 8; ++cc) {
        acc[cc][0] = make_float4(0.f, 0.f, 0.f, 0.f);
        acc[cc][1] = make_float4(0.f, 0.f, 0.f, 0.f);
    }

    #pragma unroll
    for (int c = 0; c < 8; ++c) {
        if (c < 7) {   // prefetch chunk c+1 into other buffer
            #pragma unroll
            for (int q = 0; q < 4; ++q) {
                const int lr = 16 * w + 4 * q;
                const int gr = wrow_map(128 * (c + 1) + lr + wdr);
                __builtin_amdgcn_global_load_lds(Wm + (size_t)gr * 2000 + wcol,
                                                 &s_w[(c + 1) & 1][lr * 64], 16, 0, 0);
            }
            asm volatile("s_waitcnt vmcnt(4)" ::: "memory");
        } else {
            asm volatile("s_waitcnt vmcnt(0)" ::: "memory");
        }
        __builtin_amdgcn_sched_barrier(0);
        const float* wb = s_w[c & 1];
        #pragma unroll
        for (int i = 0; i < 4; ++i) {
            const int lr = 16 * w + 4 * i + ks;             // row&3 == ks
            const float4 wA = *(const float4*)&wb[lr * 64 + woffA];
            const float4 wB = *(const float4*)&wb[lr * 64 + woffB];
            const float* xr = &s_x[(128 * c + lr) * 16 + bg * 8];
            const float4 xA = *(const float4*)(xr);
            const float4 xB = *(const float4*)(xr + 4);
#define ACCUM(CC, WS) \
    acc[CC][0].x = fmaf(WS, xA.x, acc[CC][0].x); \
    acc[CC][0].y = fmaf(WS, xA.y, acc[CC][0].y); \
    acc[CC][0].z = fmaf(WS, xA.z, acc[CC][0].z); \
    acc[CC][0].w = fmaf(WS, xA.w, acc[CC][0].w); \
    acc[CC][1].x = fmaf(WS, xB.x, acc[CC][1].x); \
    acc[CC][1].y = fmaf(WS, xB.y, acc[CC][1].y); \
    acc[CC][1].z = fmaf(WS, xB.z, acc[CC][1].z); \
    acc[CC][1].w = fmaf(WS, xB.w, acc[CC][1].w);
            ACCUM(0, wA.x) ACCUM(1, wA.y) ACCUM(2, wA.z) ACCUM(3, wA.w)
            ACCUM(4, wB.x) ACCUM(5, wB.y) ACCUM(6, wB.z) ACCUM(7, wB.w)
#undef ACCUM
        }
    }

    // ---- ks-combine: DPP quad butterfly (f32), then ks==0 writes partials
    #pragma unroll
    for (int cc = 0; cc < 8; ++cc) {
        #pragma unroll
        for (int j = 0; j < 2; ++j) {
            float4& v = acc[cc][j];
            v.x = qreduce(v.x);
            v.y = qreduce(v.y);
            v.z = qreduce(v.z);
            v.w = qreduce(v.w);
        }
    }
    if (ks == 0) {   // wave-local segment of s_w[0] (its own rows 16w..16w+15)
        float* p0 = &s_w[0][w * 1024];
        #pragma unroll
        for (int cc = 0; cc < 8; ++cc) {
            const int col = cg * 8 + cc;
            #pragma unroll
            for (int j = 0; j < 2; ++j) {
                const int pos = (bg * 8 + 4 * j) ^ (4 * (cg & 3));
                *(float4*)&p0[col * 16 + pos] = acc[cc][j];
            }
        }
    }
    __syncthreads();   // the ONLY barrier this step

    // ---- gates: f64 combine of 8 wave-partials + LSTM cell ----
    if (tid < 256) {
        const int gb = tid & 15;          // batch lane
        const int uu = tid >> 4;
        const int u = ut * 16 + uu;
        if (u < Hn) {
            const float* P = &s_w[0][0];
            double z[4];
            #pragma unroll
            for (int g = 0; g < 4; ++g) {
                const int col = g * 16 + uu;
                const int pos = col * 16 + (gb ^ (4 * ((col >> 3) & 3)));
                double zz = 0.0;
                #pragma unroll
                for (int q = 0; q < 8; ++q)
                    zz += (double)P[q * 1024 + pos];
                z[g] = zz + (double)bv[g * 500 + u];
            }
            const double gi = 1.0 / (1.0 + exp(-z[0]));
            const double gf = 1.0 / (1.0 + exp(-(z[2] + 1.0)));
            const double go_ = 1.0 / (1.0 + exp(-z[3]));
            const int ci = u * 64 + b0 + gb;
            const double cnew = gf * cb[ci] + gi * tanh(z[1]);
            cb[ci] = cnew;
            houtT[ci] = (float)(go_ * tanh(cnew));
        }
    }
}

// ---------- dense head (f64 accumulation), validated since round 1 ----------
extern "C" __global__ void __launch_bounds__(256)
head1(const char* __restrict__ ws_c, const float* __restrict__ w1,
      const float* __restrict__ bw1, char* __restrict__ ws)
{
    const float* lastT = (const float*)(ws_c + OFF_H2);  // h2 phase 0 (t=399)
    float* d1p = (float*)(ws + OFF_D1);
    const int o = blockIdx.x * 256 + threadIdx.x;        // 200 blocks
    if (o >= 51200) return;
    const int b = o / 800, j = o - b * 800;
    double acc = 0;
    for (int kk = 0; kk < 500; ++kk)
        acc += (double)lastT[kk * 64 + b] * (double)w1[(size_t)kk * 800 + j];
    acc += (double)bw1[j];
    d1p[b * 800 + j] = (float)fmax(acc, 0.0);
}

extern "C" __global__ void __launch_bounds__(256)
head2(const char* __restrict__ ws_c, const float* __restrict__ w2,
      const float* __restrict__ bw2, char* __restrict__ ws)
{
    const float* d1p = (const float*)(ws_c + OFF_D1);
    float* d2p = (float*)(ws + OFF_D2);
    const int o = blockIdx.x * 256 + threadIdx.x;        // 25 blocks
    if (o >= 6400) return;
    const int b = o / 100, j = o - b * 100;
    const float* dr = d1p + b * 800;
    double acc = 0;
    for (int kk = 0; kk < 800; ++kk)
        acc += (double)dr[kk] * (double)w2[(size_t)kk * 100 + j];
    acc += (double)bw2[j];
    d2p[b * 100 + j] = (float)fmax(acc, 0.0);
}

extern "C" __global__ void __launch_bounds__(128)
head3(const char* __restrict__ ws_c, const float* __restrict__ wpm,
      const float* __restrict__ bpv, float* __restrict__ out)
{
    const float* d2p = (const float*)(ws_c + OFF_D2);
    const int tid = threadIdx.x;                         // 1 block, 128 thr
    const int b = tid >> 1, cc = tid & 1;
    const float* dr = d2p + b * 100;
    double acc = 0;
    for (int kk = 0; kk < 100; ++kk)
        acc += (double)dr[kk] * (double)wpm[kk * 2 + cc];
    acc += (double)bpv[cc];
    out[b * 2 + cc] = (float)acc;
}

extern "C" void kernel_launch(void* const* d_in, const int* in_sizes, int n_in,
                              void* d_out, int out_size, void* d_ws, size_t ws_size,
                              hipStream_t stream) {
    const int* X = (const int*)d_in[0];
    const float* embed = (const float*)d_in[1];
    const float* k1 = (const float*)d_in[2];
    const float* b1 = (const float*)d_in[3];
    const float* k2 = (const float*)d_in[4];
    const float* b2 = (const float*)d_in[5];
    const float* w1 = (const float*)d_in[6];
    const float* bw1 = (const float*)d_in[7];
    const float* w2 = (const float*)d_in[8];
    const float* bw2 = (const float*)d_in[9];
    const float* wpm = (const float*)d_in[10];
    const float* bpv = (const float*)d_in[11];
    char* ws = (char*)d_ws;

    const int use_xe = (ws_size >= WS_NEED) ? 1 : 0;
    float* xe = (float*)(ws + OFF_XE);

    // zero h (both phases) + c (f64) — captured: clean state every replay
    hipMemsetAsync(d_ws, 0, WS_ZERO, stream);
    if (use_xe)
        xprep<<<400, 256, 0, stream>>>(X, embed, xe);

    for (int s = 0; s <= Tn; ++s)
        rnn_step<<<256, NTHR, 0, stream>>>(X, embed, k1, b1, k2, b2, ws,
                                           xe, use_xe, s);

    head1<<<200, 256, 0, stream>>>(ws, w1, bw1, ws);
    head2<<<25, 256, 0, stream>>>(ws, w2, bw2, ws);
    head3<<<1, 128, 0, stream>>>(ws, wpm, bpv, (float*)d_out);
}

// Round 15
// 5757.013 us; speedup vs baseline: 1.0603x; 1.0603x over previous
//
#include <hip/hip_runtime.h>

// RNNModel: 2-layer LSTM (B=64,T=400,E=H=500) + MLP head (800->100->2).
// FINAL (= round 11, measured best 5.78ms, absmax 0.0):
//  - one dispatch per grid-step (401 nodes; kernel boundaries = grid barrier,
//    measured 40us/step cheaper than an in-kernel flag barrier).
//  - per dispatch: L0 computes t=s (blocks 0..124 slices), L1 computes t=s-1,
//    layers pipelined; block = (L, 16-batch tile, 16-unit slice), 1 block/CU.
//  - xe pre-pass (ws-guarded): xe[t][k][b] = embed[X[b][t]][k] so L0 staging
//    is pure global_load_lds like L1 (no in-loop transpose).
//  - wave-local everything: wave w owns k-rows {128c+16w..+15} for weights
//    and x; depth-1 weight prefetch with counted s_waitcnt vmcnt(4) (never
//    drained by a barrier); ONE __syncthreads per step (before gate combine).
//  - K-loop: 8col x 8batch per lane, 16 ds_read_b128 per 256 wave-FMA;
//    ks-reduce via DPP quad butterfly (pure VALU).
//  - numerics (absmax 0.0 vs np across 10 runs): f32 serial 32-term per-lane
//    chunks, f32 DPP tree, f64 combine over 8 wave partials, f64 gates/cell
//    (c in ws), f32 h, f64 dense head.
// Probed and rejected: deeper prefetch (-26%), gate pair-split (0%), LDS
// bank swizzles (-6%), bigger tiles (-23%): step is serial-latency-bound.

#define NTHR 512
#define Tn 400
#define Hn 500

#define OFF_H1 0            // float [2][500*64] transposed h1
#define OFF_H2 256000       // float [2][500*64] transposed h2
#define OFF_C1 512000       // double [500*64] c1 (index u*64+b)
#define OFF_C2 768000       // double [500*64] c2
#define OFF_D1 1024000      // float [64*800]
#define OFF_D2 1228800      // float [64*100]
#define OFF_XE 1254400      // float [400][500][64] transposed embed gather
#define WS_NEED (1254400ull + 51200000ull)
#define WS_ZERO 1024000     // zero h+c; d1/d2/xe fully overwritten

__device__ __forceinline__ float qreduce(float v) {
    // butterfly over lanes ^1 and ^2 (quad_perm DPP, pure VALU pipe)
    int t = __builtin_amdgcn_update_dpp(0, __float_as_int(v), 0xB1, 0xF, 0xF, true);
    v += __int_as_float(t);
    t = __builtin_amdgcn_update_dpp(0, __float_as_int(v), 0x4E, 0xF, 0xF, true);
    v += __int_as_float(t);
    return v;
}

__device__ __forceinline__ int wrow_map(int r) {
    // padded LDS row -> global weight row (zero-x rows: any valid row)
    int r2 = (r >= 512) ? r - 12 : r;
    if ((r >= 500 && r < 512) || r >= 1012) r2 = 0;
    return r2;
}

// ---------- pre-pass: xe[t][k][b] = embed[X[b][t]][k] ----------
extern "C" __global__ void __launch_bounds__(256)
xprep(const int* __restrict__ X, const float* __restrict__ embed,
      float* __restrict__ xe)
{
    const int t = blockIdx.x;           // 400 blocks
    const int b = threadIdx.x & 63;
    const int kq0 = threadIdx.x >> 6;   // 0..3
    const float* er = embed + (size_t)X[b * Tn + t] * 500;
    float* dst = xe + (size_t)t * 32000;
    for (int kq = kq0; kq < 125; kq += 4) {
        const float4 v = *(const float4*)(er + 4 * kq);
        dst[(4 * kq + 0) * 64 + b] = v.x;
        dst[(4 * kq + 1) * 64 + b] = v.y;
        dst[(4 * kq + 2) * 64 + b] = v.z;
        dst[(4 * kq + 3) * 64 + b] = v.w;
    }
}

extern "C" __global__ void __launch_bounds__(NTHR)
rnn_step(const int* __restrict__ X, const float* __restrict__ embed,
         const float* __restrict__ k1, const float* __restrict__ b1g,
         const float* __restrict__ k2, const float* __restrict__ b2g,
         char* __restrict__ ws, const float* __restrict__ xe, int use_xe,
         int s)
{
    __shared__ float s_x[16384];     // [1024 padded-k][16 b]
    __shared__ float s_w[2][8192];   // dbuf [128 rows][64 cols, row-XOR swz]
    // partials alias s_w[0]: wave w's segment == its own rows 16w..16w+15

    float* h1b = (float*)(ws + OFF_H1);
    float* h2b = (float*)(ws + OFF_H2);

    const int bid = blockIdx.x;
    const int tid = threadIdx.x;
    const int rr_ = bid >> 3;
    const int slice = (bid & 7) * 8 + (rr_ >> 2);  // XCD-grouped duplicates
    const int btile = rr_ & 3;
    const int L = slice >> 5;
    const int ut = slice & 31;          // units ut*16..+15
    const int b0 = btile * 16;

    const bool active = L ? (s >= 1) : (s < Tn);
    if (!active) return;

    const int w = tid >> 6;             // wave
    const int l = tid & 63;
    const int ks = l & 3;               // K sublane
    const int cg = (l >> 2) & 7;        // 8-col group
    const int bg = l >> 5;              // 8-batch half

    const float* Wm = L ? k2 : k1;      // [1000][2000], col = g*500+u
    const float* bv = L ? b2g : b1g;
    double* cb = (double*)(ws + (L ? OFF_C2 : OFF_C1));

    const int cur = s & 1, prv = cur ^ 1;
    const float* h1p = h1b + prv * 32000;
    const float* h2p = h2b + prv * 32000;
    float* houtT = (L ? h2b : h1b) + cur * 32000;
    const int t = L ? (s - 1) : s;
    const float* hlow = h1p;                    // padded rows 0..499
    const float* hhigh = L ? h2p : h1p;         // padded rows 512..1011

    // ---- weight gll source mapping (dest linear; source col permuted) ----
    const int wdr = l >> 4;                     // dest row within 4-row inst
    const int wcq = l & 15;
    const int c_l = (4 * wcq) ^ (wdr << 3);     // logical col for this lane
    const int wcol = (c_l >> 4) * 500 + min(ut * 16 + (c_l & 15), 496);

    // ---- x gll lane consts ----
    const int xr4 = l >> 2;
    const int xj = (l & 3) * 4;

    // =================== x staging (wave-local rows) ===================
    if (use_xe || L == 1) {
        // unified pure-gll path
        const float* srcLow = L ? hlow : (xe + (size_t)t * 32000);
        const float* srcHigh = hhigh;
        #pragma unroll
        for (int c = 0; c < 8; ++c) {
            if (w < 7 || (c != 3 && c != 7)) {
                const int base = 128 * c + 16 * w;
                const float* src = (c < 4)
                    ? (srcLow + (base + xr4) * 64 + b0 + xj)
                    : (srcHigh + (base - 512 + xr4) * 64 + b0 + xj);
                __builtin_amdgcn_global_load_lds(src, &s_x[base * 16], 16, 0, 0);
            }
        }
        if (w == 7) {
            if (l < 16) {
                const int r = 496 + (l >> 2);       // <- srcLow rows 496..499
                const float4 v = *(const float4*)(srcLow + r * 64 + b0 + (l & 3) * 4);
                *(float4*)&s_x[r * 16 + (l & 3) * 4] = v;
                const int r2 = 1008 + (l >> 2);     // <- srcHigh rows 496..499
                const float4 v2 = *(const float4*)(srcHigh + (r2 - 512) * 64 + b0 + (l & 3) * 4);
                *(float4*)&s_x[r2 * 16 + (l & 3) * 4] = v2;
            }
            if (l < 48) {
                const int r = 500 + (l >> 2);
                *(float4*)&s_x[r * 16 + 4 * (l & 3)] = make_float4(0.f, 0.f, 0.f, 0.f);
                const int r2 = 1012 + (l >> 2);
                *(float4*)&s_x[r2 * 16 + 4 * (l & 3)] = make_float4(0.f, 0.f, 0.f, 0.f);
            }
        }
    } else {
        // fallback (ws too small): r8's L0 embed-transpose path, verbatim
        const int eb = l & 15, j = l >> 4;
        const int xid = X[(b0 + eb) * Tn + t];
        const float* er = embed + (size_t)xid * 500;
        #pragma unroll
        for (int c = 0; c < 4; ++c) {
            if (w < 7 || c < 3) {
                const int base = 128 * c + 16 * w;
                const float4 v = *(const float4*)(er + base + 4 * j);
                float* d = &s_x[(base + 4 * j) * 16 + eb];
                d[0] = v.x; d[16] = v.y; d[32] = v.z; d[48] = v.w;
            }
        }
        #pragma unroll
        for (int c = 4; c < 8; ++c) {
            if (!(w == 7 && c == 7)) {
                const int base = 128 * c + 16 * w;
                const float* src = hhigh + (base - 512 + xr4) * 64 + b0 + xj;
                __builtin_amdgcn_global_load_lds(src, &s_x[base * 16], 16, 0, 0);
            }
        }
        if (w == 7) {
            {   // rows 496..499 <- embed cols 496..499
                const int r = 496 + (l >> 4);
                const int b = l & 15;
                const float vv = embed[(size_t)X[(b0 + b) * Tn + t] * 500 + r];
                s_x[r * 16 + b] = vv;
            }
            if (l < 16) {               // rows 1008..1011 <- h1 rows 496..499
                const int r = 1008 + (l >> 2);
                const float4 v = *(const float4*)(hhigh + (r - 512) * 64 + b0 + (l & 3) * 4);
                *(float4*)&s_x[r * 16 + (l & 3) * 4] = v;
            }
            if (l < 48) {               // zero rows 500..511, 1012..1023
                const int r = 500 + (l >> 2);
                *(float4*)&s_x[r * 16 + 4 * (l & 3)] = make_float4(0.f, 0.f, 0.f, 0.f);
                const int r2 = 1012 + (l >> 2);
                *(float4*)&s_x[r2 * 16 + 4 * (l & 3)] = make_float4(0.f, 0.f, 0.f, 0.f);
            }
        }
    }
    // weight chunk 0 (wave-local rows)
    #pragma unroll
    for (int q = 0; q < 4; ++q) {
        const int lr = 16 * w + 4 * q;
        const int gr = wrow_map(lr + wdr);
        __builtin_amdgcn_global_load_lds(Wm + (size_t)gr * 2000 + wcol,
                                         &s_w[0][lr * 64], 16, 0, 0);
    }

    // ================= chunk loop: NO barriers, counted vmcnt ===========
    float4 acc[8][2];
    #pragma unroll
    for (int cc = 0; cc < 8; ++cc) {
        acc[cc][0] = make_float4(0.f, 0.f, 0.f, 0.f);
        acc[cc][1] = make_float4(0.f, 0.f, 0.f, 0.f);
    }

    #pragma unroll
    for (int c = 0; c < 8; ++c) {
        if (c < 7) {   // prefetch chunk c+1 into other buffer
            #pragma unroll
            for (int q = 0; q < 4; ++q) {
                const int lr = 16 * w + 4 * q;
                const int gr = wrow_map(128 * (c + 1) + lr + wdr);
                __builtin_amdgcn_global_load_lds(Wm + (size_t)gr * 2000 + wcol,
                                                 &s_w[(c + 1) & 1][lr * 64], 16, 0, 0);
            }
            asm volatile("s_waitcnt vmcnt(4)" ::: "memory");
        } else {
            asm volatile("s_waitcnt vmcnt(0)" ::: "memory");
        }
        __builtin_amdgcn_sched_barrier(0);
        const float* wb = s_w[c & 1];
        #pragma unroll
        for (int i = 0; i < 4; ++i) {
            const int lr = 16 * w + 4 * i + ks;             // row&3 == ks
            const float4 wA = *(const float4*)&wb[lr * 64 + ((cg ^ ks) << 3)];
            const float4 wB = *(const float4*)&wb[lr * 64 + ((cg ^ ks) << 3) + 4];
            const float* xr = &s_x[(128 * c + lr) * 16 + bg * 8];
            const float4 xA = *(const float4*)(xr);
            const float4 xB = *(const float4*)(xr + 4);
#define ACCUM(CC, WS) \
    acc[CC][0].x = fmaf(WS, xA.x, acc[CC][0].x); \
    acc[CC][0].y = fmaf(WS, xA.y, acc[CC][0].y); \
    acc[CC][0].z = fmaf(WS, xA.z, acc[CC][0].z); \
    acc[CC][0].w = fmaf(WS, xA.w, acc[CC][0].w); \
    acc[CC][1].x = fmaf(WS, xB.x, acc[CC][1].x); \
    acc[CC][1].y = fmaf(WS, xB.y, acc[CC][1].y); \
    acc[CC][1].z = fmaf(WS, xB.z, acc[CC][1].z); \
    acc[CC][1].w = fmaf(WS, xB.w, acc[CC][1].w);
            ACCUM(0, wA.x) ACCUM(1, wA.y) ACCUM(2, wA.z) ACCUM(3, wA.w)
            ACCUM(4, wB.x) ACCUM(5, wB.y) ACCUM(6, wB.z) ACCUM(7, wB.w)
#undef ACCUM
        }
    }

    // ---- ks-combine: DPP quad butterfly (f32), then ks==0 writes partials
    #pragma unroll
    for (int cc = 0; cc < 8; ++cc) {
        #pragma unroll
        for (int j = 0; j < 2; ++j) {
            float4& v = acc[cc][j];
            v.x = qreduce(v.x);
            v.y = qreduce(v.y);
            v.z = qreduce(v.z);
            v.w = qreduce(v.w);
        }
    }
    if (ks == 0) {   // wave-local segment of s_w[0] (its own rows 16w..16w+15)
        float* p0 = &s_w[0][w * 1024];
        #pragma unroll
        for (int cc = 0; cc < 8; ++cc) {
            const int col = cg * 8 + cc;
            #pragma unroll
            for (int j = 0; j < 2; ++j) {
                const int pos = (bg * 8 + 4 * j) ^ (4 * (cg & 3));
                *(float4*)&p0[col * 16 + pos] = acc[cc][j];
            }
        }
    }
    __syncthreads();   // the ONLY barrier this step

    // ---- gates: f64 combine of 8 wave-partials + LSTM cell ----
    if (tid < 256) {
        const int gb = tid & 15;          // batch lane
        const int uu = tid >> 4;
        const int u = ut * 16 + uu;
        if (u < Hn) {
            const float* P = &s_w[0][0];
            double z[4];
            #pragma unroll
            for (int g = 0; g < 4; ++g) {
                const int col = g * 16 + uu;
                const int pos = col * 16 + (gb ^ (4 * ((col >> 3) & 3)));
                double zz = 0.0;
                #pragma unroll
                for (int q = 0; q < 8; ++q)
                    zz += (double)P[q * 1024 + pos];
                z[g] = zz + (double)bv[g * 500 + u];
            }
            const double gi = 1.0 / (1.0 + exp(-z[0]));
            const double gf = 1.0 / (1.0 + exp(-(z[2] + 1.0)));
            const double go_ = 1.0 / (1.0 + exp(-z[3]));
            const int ci = u * 64 + b0 + gb;
            const double cnew = gf * cb[ci] + gi * tanh(z[1]);
            cb[ci] = cnew;
            houtT[ci] = (float)(go_ * tanh(cnew));
        }
    }
}

// ---------- dense head (f64 accumulation), validated since round 1 ----------
extern "C" __global__ void __launch_bounds__(256)
head1(const char* __restrict__ ws_c, const float* __restrict__ w1,
      const float* __restrict__ bw1, char* __restrict__ ws)
{
    const float* lastT = (const float*)(ws_c + OFF_H2);  // h2 phase 0 (t=399)
    float* d1p = (float*)(ws + OFF_D1);
    const int o = blockIdx.x * 256 + threadIdx.x;        // 200 blocks
    if (o >= 51200) return;
    const int b = o / 800, j = o - b * 800;
    double acc = 0;
    for (int kk = 0; kk < 500; ++kk)
        acc += (double)lastT[kk * 64 + b] * (double)w1[(size_t)kk * 800 + j];
    acc += (double)bw1[j];
    d1p[b * 800 + j] = (float)fmax(acc, 0.0);
}

extern "C" __global__ void __launch_bounds__(256)
head2(const char* __restrict__ ws_c, const float* __restrict__ w2,
      const float* __restrict__ bw2, char* __restrict__ ws)
{
    const float* d1p = (const float*)(ws_c + OFF_D1);
    float* d2p = (float*)(ws + OFF_D2);
    const int o = blockIdx.x * 256 + threadIdx.x;        // 25 blocks
    if (o >= 6400) return;
    const int b = o / 100, j = o - b * 100;
    const float* dr = d1p + b * 800;
    double acc = 0;
    for (int kk = 0; kk < 800; ++kk)
        acc += (double)dr[kk] * (double)w2[(size_t)kk * 100 + j];
    acc += (double)bw2[j];
    d2p[b * 100 + j] = (float)fmax(acc, 0.0);
}

extern "C" __global__ void __launch_bounds__(128)
head3(const char* __restrict__ ws_c, const float* __restrict__ wpm,
      const float* __restrict__ bpv, float* __restrict__ out)
{
    const float* d2p = (const float*)(ws_c + OFF_D2);
    const int tid = threadIdx.x;                         // 1 block, 128 thr
    const int b = tid >> 1, cc = tid & 1;
    const float* dr = d2p + b * 100;
    double acc = 0;
    for (int kk = 0; kk < 100; ++kk)
        acc += (double)dr[kk] * (double)wpm[kk * 2 + cc];
    acc += (double)bpv[cc];
    out[b * 2 + cc] = (float)acc;
}

extern "C" void kernel_launch(void* const* d_in, const int* in_sizes, int n_in,
                              void* d_out, int out_size, void* d_ws, size_t ws_size,
                              hipStream_t stream) {
    const int* X = (const int*)d_in[0];
    const float* embed = (const float*)d_in[1];
    const float* k1 = (const float*)d_in[2];
    const float* b1 = (const float*)d_in[3];
    const float* k2 = (const float*)d_in[4];
    const float* b2 = (const float*)d_in[5];
    const float* w1 = (const float*)d_in[6];
    const float* bw1 = (const float*)d_in[7];
    const float* w2 = (const float*)d_in[8];
    const float* bw2 = (const float*)d_in[9];
    const float* wpm = (const float*)d_in[10];
    const float* bpv = (const float*)d_in[11];
    char* ws = (char*)d_ws;

    const int use_xe = (ws_size >= WS_NEED) ? 1 : 0;
    float* xe = (float*)(ws + OFF_XE);

    // zero h (both phases) + c (f64) — captured: clean state every replay
    hipMemsetAsync(d_ws, 0, WS_ZERO, stream);
    if (use_xe)
        xprep<<<400, 256, 0, stream>>>(X, embed, xe);

    for (int s = 0; s <= Tn; ++s)
        rnn_step<<<256, NTHR, 0, stream>>>(X, embed, k1, b1, k2, b2, ws,
                                           xe, use_xe, s);

    head1<<<200, 256, 0, stream>>>(ws, w1, bw1, ws);
    head2<<<25, 256, 0, stream>>>(ws, w2, bw2, ws);
    head3<<<1, 128, 0, stream>>>(ws, wpm, bpv, (float*)d_out);
}